// Round 10
// baseline (61.585 us; speedup 1.0000x reference)
//
#include <hip/hip_runtime.h>

#define B_ 8
#define N_ 256
#define D_ 512
#define TI 8        // query rows per block
#define NCHUNK 32   // 512 d / 16 d per chunk

// async 16B global -> LDS. FULL-WAVE ONLY (exec-masked LDS-DMA corrupts LDS:
// dest is wave-uniform base + lane*16B for ALL lanes -- R8/R9 failure).
__device__ __forceinline__ void load_lds_16B(const float* g, float* l)
{
    __builtin_amdgcn_global_load_lds(
        (const __attribute__((address_space(1))) void*)g,
        (__attribute__((address_space(3))) void*)l, 16, 0, 0);
}

// ---------- Main kernel: TI=8, 512 threads (8 waves), grid = 256 ----------
// b = bid & 7 (batch per XCD). Thread = (j = t&255, iq = t>>8 -> 4 rows).
// Phase A: k staged via full-wave global_load_lds, 2 LDS buffers, stage c+1
//          then compute c then __syncthreads (compute >> latency, drain ~0).
//          k LDS XOR-swizzled: slot 4t holds k[t>>2][c*16+((t&3)^((t>>3)&3))*4..]
//          read with swz4 = ((j>>1)&3)<<2 -> conflict-free ds_read_b128.
// q read straight from global (wave-uniform addresses -> broadcast, L1-hot).
__global__ __launch_bounds__(512)
void manh_attn_v10(const float* __restrict__ q,
                   const float* __restrict__ k,
                   const float* __restrict__ v,
                   float* __restrict__ out)
{
    __shared__ __align__(16) float s_k[2][4096];  // 32 KB: swizzled k chunks
    __shared__ __align__(16) float s_w[TI * N_];  // 8 KB: scores -> weights
    float* s_part = &s_k[0][0];                   // 8192-float phase-C scratch

    const int t    = threadIdx.x;
    const int lane = t & 63;
    const int w    = t >> 6;                 // wave 0..7
    const int b    = blockIdx.x & 7;         // batch -> XCD locality
    const int i0   = (blockIdx.x >> 3) * TI; // 0..31 tiles

    const float* __restrict__ kb = k + (size_t)b * N_ * D_;
    const float* __restrict__ qb = q + ((size_t)(b * N_ + i0)) * D_;

    // --- k staging source (pre-swizzled global address, linear LDS dest) ---
    const int j1  = t >> 2;                      // rows 0..127 (+128 for instr 2)
    const int dg1 = (t & 3) ^ ((t >> 3) & 3);    // d-group held by slot 4t
    const float* ksrc1 = kb + (size_t)j1 * D_ + dg1 * 4;
    const float* ksrc2 = ksrc1 + (size_t)128 * D_;

#define STAGE(cc, sb)                                              \
    {                                                              \
        load_lds_16B(ksrc1 + (cc) * 16, &s_k[sb][4 * t]);          \
        load_lds_16B(ksrc2 + (cc) * 16, &s_k[sb][2048 + 4 * t]);   \
    }

    STAGE(0, 0)
    __syncthreads();                  // chunk 0 resident

    // ---- Phase A: L1 distances ----
    const int j    = t & 255;
    const int iq   = t >> 8;          // 0..1 -> rows iq*4 .. iq*4+3
    const int swz4 = ((j >> 1) & 3) << 2;
    const float* __restrict__ qrow = qb + (size_t)(iq * 4) * D_;

    float acc0 = 0.f, acc1 = 0.f, acc2 = 0.f, acc3 = 0.f;

    int buf = 0;
    for (int c = 0; c < NCHUNK; ++c) {
        if (c < NCHUNK - 1) STAGE(c + 1, buf ^ 1)

        const float* kcb = &s_k[buf][j << 4];
        #pragma unroll
        for (int dg = 0; dg < 4; ++dg) {
            const float4 k4 = *(const float4*)(kcb + ((dg << 2) ^ swz4));
            const int doff = c * 16 + dg * 4;
            const float4 q0 = *(const float4*)(qrow + doff);
            const float4 q1 = *(const float4*)(qrow + D_ + doff);
            const float4 q2 = *(const float4*)(qrow + 2 * D_ + doff);
            const float4 q3 = *(const float4*)(qrow + 3 * D_ + doff);
            acc0 += (fabsf(q0.x - k4.x) + fabsf(q0.y - k4.y)) +
                    (fabsf(q0.z - k4.z) + fabsf(q0.w - k4.w));
            acc1 += (fabsf(q1.x - k4.x) + fabsf(q1.y - k4.y)) +
                    (fabsf(q1.z - k4.z) + fabsf(q1.w - k4.w));
            acc2 += (fabsf(q2.x - k4.x) + fabsf(q2.y - k4.y)) +
                    (fabsf(q2.z - k4.z) + fabsf(q2.w - k4.w));
            acc3 += (fabsf(q3.x - k4.x) + fabsf(q3.y - k4.y)) +
                    (fabsf(q3.z - k4.z) + fabsf(q3.w - k4.w));
        }

        __syncthreads();              // drains next-chunk DMA; issued one full
        buf ^= 1;                     // compute phase (~512 cyc) earlier
    }
#undef STAGE

    // ---- scores -> LDS ----
    s_w[(iq * 4 + 0) * N_ + j] = -acc0;
    s_w[(iq * 4 + 1) * N_ + j] = -acc1;
    s_w[(iq * 4 + 2) * N_ + j] = -acc2;
    s_w[(iq * 4 + 3) * N_ + j] = -acc3;
    __syncthreads();

    // ---- softmax: wave w handles row w ----
    {
        float* row = &s_w[w * N_];
        float v0 = row[lane];
        float v1 = row[lane + 64];
        float v2 = row[lane + 128];
        float v3 = row[lane + 192];
        float m = fmaxf(fmaxf(v0, v1), fmaxf(v2, v3));
        #pragma unroll
        for (int off = 32; off; off >>= 1) m = fmaxf(m, __shfl_xor(m, off));
        const float cc = 1.4426950408889634f;
        float e0 = exp2f((v0 - m) * cc);
        float e1 = exp2f((v1 - m) * cc);
        float e2 = exp2f((v2 - m) * cc);
        float e3 = exp2f((v3 - m) * cc);
        float s = (e0 + e1) + (e2 + e3);
        #pragma unroll
        for (int off = 32; off; off >>= 1) s += __shfl_xor(s, off);
        const float r = 1.0f / s;
        row[lane]       = e0 * r;
        row[lane + 64]  = e1 * r;
        row[lane + 128] = e2 * r;
        row[lane + 192] = e3 * r;
    }
    __syncthreads();

    // ---- Phase C: out = attn @ v, all 8 rows per thread, v read once ----
    const int dq  = t & 127;
    const int jq4 = t >> 7;           // j-quarter 0..3
    const int j0  = jq4 * 64;
    const float* __restrict__ vb = v + (size_t)b * N_ * D_ + dq * 4;

    float4 a0 = make_float4(0.f,0.f,0.f,0.f), a1 = a0, a2 = a0, a3 = a0;
    float4 a4 = a0, a5 = a0, a6 = a0, a7 = a0;

#define PVROW(A, W)                                                            \
    A.x += (W).x * vv0.x + (W).y * vv1.x + (W).z * vv2.x + (W).w * vv3.x;      \
    A.y += (W).x * vv0.y + (W).y * vv1.y + (W).z * vv2.y + (W).w * vv3.y;      \
    A.z += (W).x * vv0.z + (W).y * vv1.z + (W).z * vv2.z + (W).w * vv3.z;      \
    A.w += (W).x * vv0.w + (W).y * vv1.w + (W).z * vv2.w + (W).w * vv3.w;

    #pragma unroll 2
    for (int jo = 0; jo < 64; jo += 4) {
        const int jj = j0 + jo;
        const float4 vv0 = *(const float4*)(vb + (size_t)(jj + 0) * D_);
        const float4 vv1 = *(const float4*)(vb + (size_t)(jj + 1) * D_);
        const float4 vv2 = *(const float4*)(vb + (size_t)(jj + 2) * D_);
        const float4 vv3 = *(const float4*)(vb + (size_t)(jj + 3) * D_);
        const float4 w0 = *(const float4*)&s_w[0 * N_ + jj];
        const float4 w1 = *(const float4*)&s_w[1 * N_ + jj];
        const float4 w2 = *(const float4*)&s_w[2 * N_ + jj];
        const float4 w3 = *(const float4*)&s_w[3 * N_ + jj];
        const float4 w4 = *(const float4*)&s_w[4 * N_ + jj];
        const float4 w5 = *(const float4*)&s_w[5 * N_ + jj];
        const float4 w6 = *(const float4*)&s_w[6 * N_ + jj];
        const float4 w7 = *(const float4*)&s_w[7 * N_ + jj];
        PVROW(a0, w0) PVROW(a1, w1) PVROW(a2, w2) PVROW(a3, w3)
        PVROW(a4, w4) PVROW(a5, w5) PVROW(a6, w6) PVROW(a7, w7)
    }
#undef PVROW

    // ---- reduce 4 j-quarters, two 4-row passes through s_part ----
    __syncthreads();                  // all phase-A/softmax reads of s_k done
    *(float4*)&s_part[jq4 * 2048 + 0 * 512 + dq * 4] = a0;
    *(float4*)&s_part[jq4 * 2048 + 1 * 512 + dq * 4] = a1;
    *(float4*)&s_part[jq4 * 2048 + 2 * 512 + dq * 4] = a2;
    *(float4*)&s_part[jq4 * 2048 + 3 * 512 + dq * 4] = a3;
    __syncthreads();
    {
        const int r  = t >> 7;
        const int d4 = (t & 127) * 4;
        const float4 p0 = *(const float4*)&s_part[0 * 2048 + r * 512 + d4];
        const float4 p1 = *(const float4*)&s_part[1 * 2048 + r * 512 + d4];
        const float4 p2 = *(const float4*)&s_part[2 * 2048 + r * 512 + d4];
        const float4 p3 = *(const float4*)&s_part[3 * 2048 + r * 512 + d4];
        float4 s;
        s.x = (p0.x + p1.x) + (p2.x + p3.x);
        s.y = (p0.y + p1.y) + (p2.y + p3.y);
        s.z = (p0.z + p1.z) + (p2.z + p3.z);
        s.w = (p0.w + p1.w) + (p2.w + p3.w);
        *(float4*)(out + ((size_t)(b * N_ + i0 + r)) * D_ + d4) = s;
    }
    __syncthreads();
    *(float4*)&s_part[jq4 * 2048 + 0 * 512 + dq * 4] = a4;
    *(float4*)&s_part[jq4 * 2048 + 1 * 512 + dq * 4] = a5;
    *(float4*)&s_part[jq4 * 2048 + 2 * 512 + dq * 4] = a6;
    *(float4*)&s_part[jq4 * 2048 + 3 * 512 + dq * 4] = a7;
    __syncthreads();
    {
        const int r  = t >> 7;
        const int d4 = (t & 127) * 4;
        const float4 p0 = *(const float4*)&s_part[0 * 2048 + r * 512 + d4];
        const float4 p1 = *(const float4*)&s_part[1 * 2048 + r * 512 + d4];
        const float4 p2 = *(const float4*)&s_part[2 * 2048 + r * 512 + d4];
        const float4 p3 = *(const float4*)&s_part[3 * 2048 + r * 512 + d4];
        float4 s;
        s.x = (p0.x + p1.x) + (p2.x + p3.x);
        s.y = (p0.y + p1.y) + (p2.y + p3.y);
        s.z = (p0.z + p1.z) + (p2.z + p3.z);
        s.w = (p0.w + p1.w) + (p2.w + p3.w);
        *(float4*)(out + ((size_t)(b * N_ + i0 + 4 + r)) * D_ + d4) = s;
    }
}

extern "C" void kernel_launch(void* const* d_in, const int* in_sizes, int n_in,
                              void* d_out, int out_size, void* d_ws, size_t ws_size,
                              hipStream_t stream)
{
    const float* q = (const float*)d_in[0];
    const float* k = (const float*)d_in[1];
    const float* v = (const float*)d_in[2];
    float* out = (float*)d_out;

    manh_attn_v10<<<dim3(B_ * (N_ / TI)), dim3(512), 0, stream>>>(q, k, v, out);
}

// Round 11
// 43.553 us; speedup vs baseline: 1.4140x; 1.4140x over previous
//
#include <hip/hip_runtime.h>

#define B_ 8
#define N_ 256
#define D_ 512
#define TI 4        // query rows per block
#define NCHUNK 32   // 512 d / 16 d per chunk

// async 16B global -> LDS. FULL-WAVE ONLY (exec-masked LDS-DMA corrupts LDS).
__device__ __forceinline__ void load_lds_16B(const float* g, float* l)
{
    __builtin_amdgcn_global_load_lds(
        (const __attribute__((address_space(1))) void*)g,
        (__attribute__((address_space(3))) void*)l, 16, 0, 0);
}

// ---------- Main kernel: TI=4, 256 threads (4 waves), grid = 512 ----------
// b = bid & 7 (batch per XCD), tile = bid >> 3. 36 KB LDS -> 4 blocks/CU.
// Phase A: k staged via full-wave global_load_lds, 2 LDS buffers, stage c+1
//          then compute c then __syncthreads. Co-resident blocks cover drains.
//          k LDS XOR-swizzle (verified v10): slot 4t+1024m holds
//          k[(t>>2)+64m][c*16 + ((t&3)^((t>>3)&3))*4 ..+3];
//          read row j=t with swz4 = ((t>>1)&3)<<2.
// q read from global: block-uniform addresses -> scalar s_load pipe.
// Scores accumulate fully in-thread (j = t, rows 0..3) -> no score reduce.
__global__ __launch_bounds__(256, 4)
void manh_attn_v11(const float* __restrict__ q,
                   const float* __restrict__ k,
                   const float* __restrict__ v,
                   float* __restrict__ out)
{
    __shared__ __align__(16) float s_k[2][4096];  // 32 KB: swizzled k chunks
    __shared__ __align__(16) float s_w[TI * N_];  // 4 KB: scores -> weights
    float* s_part = &s_k[0][0];                   // phase-C reduce scratch alias

    const int t    = threadIdx.x;
    const int lane = t & 63;
    const int w    = t >> 6;                 // wave 0..3
    const int b    = blockIdx.x & 7;         // batch -> XCD locality
    const int i0   = (blockIdx.x >> 3) * TI; // 0..63 tiles

    const float* __restrict__ kb = k + (size_t)b * N_ * D_;
    const float* __restrict__ qb = q + ((size_t)(b * N_ + i0)) * D_;

    // --- k staging source (pre-swizzled global address, linear LDS dest) ---
    const int dg = (t & 3) ^ ((t >> 3) & 3);
    const float* ksrc0 = kb + (size_t)(t >> 2) * D_ + dg * 4;

#define STAGE(cc, sb)                                                          \
    {                                                                          \
        load_lds_16B(ksrc0 + (cc) * 16,                   &s_k[sb][4 * t]);            \
        load_lds_16B(ksrc0 + (size_t) 64 * D_ + (cc) * 16, &s_k[sb][4 * t + 1024]);    \
        load_lds_16B(ksrc0 + (size_t)128 * D_ + (cc) * 16, &s_k[sb][4 * t + 2048]);    \
        load_lds_16B(ksrc0 + (size_t)192 * D_ + (cc) * 16, &s_k[sb][4 * t + 3072]);    \
    }

    STAGE(0, 0)
    __syncthreads();                  // chunk 0 resident

    // ---- Phase A: L1 distances (thread = column j = t, rows 0..3) ----
    const int swz4 = ((t >> 1) & 3) << 2;

    float acc0 = 0.f, acc1 = 0.f, acc2 = 0.f, acc3 = 0.f;

    int buf = 0;
    for (int c = 0; c < NCHUNK; ++c) {
        if (c < NCHUNK - 1) STAGE(c + 1, buf ^ 1)

        const float* kcb = &s_k[buf][t << 4];
        #pragma unroll
        for (int dgi = 0; dgi < 4; ++dgi) {
            const float4 k4 = *(const float4*)(kcb + ((dgi << 2) ^ swz4));
            const int doff = c * 16 + dgi * 4;
            const float4 q0 = *(const float4*)(qb + doff);              // block-
            const float4 q1 = *(const float4*)(qb + D_ + doff);         // uniform
            const float4 q2 = *(const float4*)(qb + 2 * D_ + doff);     // -> s_load
            const float4 q3 = *(const float4*)(qb + 3 * D_ + doff);
            acc0 += (fabsf(q0.x - k4.x) + fabsf(q0.y - k4.y)) +
                    (fabsf(q0.z - k4.z) + fabsf(q0.w - k4.w));
            acc1 += (fabsf(q1.x - k4.x) + fabsf(q1.y - k4.y)) +
                    (fabsf(q1.z - k4.z) + fabsf(q1.w - k4.w));
            acc2 += (fabsf(q2.x - k4.x) + fabsf(q2.y - k4.y)) +
                    (fabsf(q2.z - k4.z) + fabsf(q2.w - k4.w));
            acc3 += (fabsf(q3.x - k4.x) + fabsf(q3.y - k4.y)) +
                    (fabsf(q3.z - k4.z) + fabsf(q3.w - k4.w));
        }

        __syncthreads();              // drains c+1 DMA (issued 1 compute ago)
        buf ^= 1;
    }
#undef STAGE

    // ---- scores -> LDS ----
    s_w[0 * N_ + t] = -acc0;
    s_w[1 * N_ + t] = -acc1;
    s_w[2 * N_ + t] = -acc2;
    s_w[3 * N_ + t] = -acc3;
    __syncthreads();

    // ---- softmax: wave w handles row w (TI == 4 waves) ----
    {
        float* row = &s_w[w * N_];
        float v0 = row[lane];
        float v1 = row[lane + 64];
        float v2 = row[lane + 128];
        float v3 = row[lane + 192];
        float m = fmaxf(fmaxf(v0, v1), fmaxf(v2, v3));
        #pragma unroll
        for (int off = 32; off; off >>= 1) m = fmaxf(m, __shfl_xor(m, off));
        const float cc = 1.4426950408889634f;
        float e0 = exp2f((v0 - m) * cc);
        float e1 = exp2f((v1 - m) * cc);
        float e2 = exp2f((v2 - m) * cc);
        float e3 = exp2f((v3 - m) * cc);
        float s = (e0 + e1) + (e2 + e3);
        #pragma unroll
        for (int off = 32; off; off >>= 1) s += __shfl_xor(s, off);
        const float r = 1.0f / s;
        row[lane]       = e0 * r;
        row[lane + 64]  = e1 * r;
        row[lane + 128] = e2 * r;
        row[lane + 192] = e3 * r;
    }
    __syncthreads();

    // ---- Phase C: out = attn @ v, 4 rows per thread, v read once ----
    // thread: d-quad dq = t&127, j-half jh = t>>7 (128 j each)
    const int dq = t & 127;
    const int jh = t >> 7;
    const int j0 = jh * 128;
    const float* __restrict__ vb = v + (size_t)b * N_ * D_ + dq * 4;

    float4 a0 = make_float4(0.f,0.f,0.f,0.f), a1 = a0, a2 = a0, a3 = a0;

#define PVROW(A, W)                                                            \
    A.x += (W).x * vv0.x + (W).y * vv1.x + (W).z * vv2.x + (W).w * vv3.x;      \
    A.y += (W).x * vv0.y + (W).y * vv1.y + (W).z * vv2.y + (W).w * vv3.y;      \
    A.z += (W).x * vv0.z + (W).y * vv1.z + (W).z * vv2.z + (W).w * vv3.z;      \
    A.w += (W).x * vv0.w + (W).y * vv1.w + (W).z * vv2.w + (W).w * vv3.w;

    #pragma unroll 2
    for (int jo = 0; jo < 128; jo += 4) {
        const int jj = j0 + jo;
        const float4 vv0 = *(const float4*)(vb + (size_t)(jj + 0) * D_);
        const float4 vv1 = *(const float4*)(vb + (size_t)(jj + 1) * D_);
        const float4 vv2 = *(const float4*)(vb + (size_t)(jj + 2) * D_);
        const float4 vv3 = *(const float4*)(vb + (size_t)(jj + 3) * D_);
        const float4 w0 = *(const float4*)&s_w[0 * N_ + jj];
        const float4 w1 = *(const float4*)&s_w[1 * N_ + jj];
        const float4 w2 = *(const float4*)&s_w[2 * N_ + jj];
        const float4 w3 = *(const float4*)&s_w[3 * N_ + jj];
        PVROW(a0, w0) PVROW(a1, w1) PVROW(a2, w2) PVROW(a3, w3)
    }
#undef PVROW

    // ---- reduce 2 j-halves through s_part (s_k alias; phase A long done) ----
    *(float4*)&s_part[jh * 2048 + 0 * 512 + dq * 4] = a0;
    *(float4*)&s_part[jh * 2048 + 1 * 512 + dq * 4] = a1;
    *(float4*)&s_part[jh * 2048 + 2 * 512 + dq * 4] = a2;
    *(float4*)&s_part[jh * 2048 + 3 * 512 + dq * 4] = a3;
    __syncthreads();

    #pragma unroll
    for (int i = 0; i < 2; ++i) {
        const int e  = t + 256 * i;       // 0..511 float4-slots
        const int r  = e >> 7;            // row 0..3
        const int d4 = (e & 127) * 4;
        const float4 p0 = *(const float4*)&s_part[0 * 2048 + r * 512 + d4];
        const float4 p1 = *(const float4*)&s_part[1 * 2048 + r * 512 + d4];
        float4 s;
        s.x = p0.x + p1.x; s.y = p0.y + p1.y;
        s.z = p0.z + p1.z; s.w = p0.w + p1.w;
        *(float4*)(out + ((size_t)(b * N_ + i0 + r)) * D_ + d4) = s;
    }
}

extern "C" void kernel_launch(void* const* d_in, const int* in_sizes, int n_in,
                              void* d_out, int out_size, void* d_ws, size_t ws_size,
                              hipStream_t stream)
{
    const float* q = (const float*)d_in[0];
    const float* k = (const float*)d_in[1];
    const float* v = (const float*)d_in[2];
    float* out = (float*)d_out;

    manh_attn_v11<<<dim3(B_ * (N_ / TI)), dim3(256), 0, stream>>>(q, k, v, out);
}

// Round 12
// 38.158 us; speedup vs baseline: 1.6140x; 1.1414x over previous
//
#include <hip/hip_runtime.h>

#define B_ 8
#define N_ 256
#define D_ 512

// async 16B global -> LDS. FULL-WAVE ONLY (exec-masked LDS-DMA corrupts LDS).
__device__ __forceinline__ void load_lds_16B(const float* g, float* l)
{
    __builtin_amdgcn_global_load_lds(
        (const __attribute__((address_space(1))) void*)g,
        (__attribute__((address_space(3))) void*)l, 16, 0, 0);
}

// ================= Kernel A: scores S[b][i][j] = -sum_d |q-k| =============
// grid 1024: b=bid&7, itile=(bid>>3)&31 -> 8 rows, jq=bid>>8 -> 64 j.
// 256 thr: thread = column j = t&63; wave w owns rows {ibase+2w, +1}.
// k staged via v11-verified swizzled DMA: 64-d chunks, dbuf, 8 barriers.
//   slot [qh*1024 + 4t] holds k[jbase+(t>>2)][c*64 + qh*16 + ((t&3)^((t>>3)&3))*4]
//   read row j, d-group dgi: addr = (dgi>>2)*1024 + j*16 + (((dgi&3)<<2)^swz4),
//   swz4 = ((j>>1)&3)<<2.
// q rows wave-uniform (readfirstlane) -> scalar s_load pipe.
__global__ __launch_bounds__(256)
void manh_scores(const float* __restrict__ q,
                 const float* __restrict__ k,
                 float* __restrict__ S)
{
    __shared__ __align__(16) float s_k[2][4096];   // 32 KB: one 64-d chunk dbuf

    const int t     = threadIdx.x;
    const int b     = blockIdx.x & 7;          // batch -> XCD locality
    const int itile = (blockIdx.x >> 3) & 31;
    const int jq    = blockIdx.x >> 8;         // 0..3
    const int ibase = itile * 8;
    const int jbase = jq * 64;

    const float* __restrict__ kb = k + (size_t)b * N_ * D_;

    // --- staging source (pre-swizzled global, linear LDS dest) ---
    const int dg = (t & 3) ^ ((t >> 3) & 3);
    const float* ksrc = kb + (size_t)(jbase + (t >> 2)) * D_ + dg * 4;

#define STAGEA(cc, sb)                                              \
    {                                                               \
        load_lds_16B(ksrc + (cc) * 64,      &s_k[sb][4 * t]);       \
        load_lds_16B(ksrc + (cc) * 64 + 16, &s_k[sb][1024 + 4 * t]);\
        load_lds_16B(ksrc + (cc) * 64 + 32, &s_k[sb][2048 + 4 * t]);\
        load_lds_16B(ksrc + (cc) * 64 + 48, &s_k[sb][3072 + 4 * t]);\
    }

    STAGEA(0, 0)
    __syncthreads();                       // chunk 0 resident

    const int w    = t >> 6;               // wave id (uniform per wave)
    const int j    = t & 63;
    const int swz4 = ((j >> 1) & 3) << 2;
    // force scalar (SGPR) q base: rows are wave-uniform
    const int row0 = __builtin_amdgcn_readfirstlane(ibase + 2 * w);
    const float* __restrict__ qrow = q + ((size_t)(b * N_ + row0)) * D_;

    float acc0 = 0.f, acc1 = 0.f;

    int buf = 0;
    for (int c = 0; c < 8; ++c) {          // 8 chunks x 64 d
        if (c < 7) STAGEA(c + 1, buf ^ 1)

        const float* kcb = &s_k[buf][0];
        #pragma unroll
        for (int dgi = 0; dgi < 16; ++dgi) {
            const float4 k4 = *(const float4*)
                (kcb + (dgi >> 2) * 1024 + (j << 4) + (((dgi & 3) << 2) ^ swz4));
            const int doff = c * 64 + dgi * 4;
            const float4 q0 = *(const float4*)(qrow + doff);
            const float4 q1 = *(const float4*)(qrow + D_ + doff);
            acc0 += (fabsf(q0.x - k4.x) + fabsf(q0.y - k4.y)) +
                    (fabsf(q0.z - k4.z) + fabsf(q0.w - k4.w));
            acc1 += (fabsf(q1.x - k4.x) + fabsf(q1.y - k4.y)) +
                    (fabsf(q1.z - k4.z) + fabsf(q1.w - k4.w));
        }

        __syncthreads();                   // chunk c+1 DMA issued ~512 cyc ago
        buf ^= 1;
    }
#undef STAGEA

    float* Sp = S + (size_t)b * N_ * N_ + (size_t)(ibase + 2 * w) * N_ + jbase + j;
    Sp[0]  = -acc0;                        // row ibase+2w   (64B/wave coalesced)
    Sp[N_] = -acc1;                        // row ibase+2w+1
}

// ================= Kernel B: softmax(S) @ v ================================
// grid 1024: b=bid&7, itile=(bid>>3)&63 -> 4 rows, dh=bid>>9 -> 256 d-half.
// Softmax recomputed per d-half (cheap); s_w PV reads wave-uniform broadcast.
__global__ __launch_bounds__(256)
void manh_sm_pv(const float* __restrict__ S,
                const float* __restrict__ v,
                float* __restrict__ out)
{
    __shared__ __align__(16) float s_w[4 * N_];      // 4 KB
    __shared__ __align__(16) float s_part[4 * 1024]; // 16 KB: jh x 4 rows x 256 d

    const int t     = threadIdx.x;
    const int lane  = t & 63;
    const int w     = t >> 6;
    const int b     = blockIdx.x & 7;
    const int itile = (blockIdx.x >> 3) & 63;
    const int dh    = blockIdx.x >> 9;     // 0..1
    const int i0    = itile * 4;

    // ---- load scores: 4 rows x 256 j = contiguous 1024 floats ----
    *(float4*)&s_w[4 * t] =
        *(const float4*)(S + (size_t)b * N_ * N_ + (size_t)i0 * N_ + 4 * t);
    __syncthreads();

    // ---- softmax: wave w handles row w ----
    {
        float* row = &s_w[w * N_];
        float v0 = row[lane];
        float v1 = row[lane + 64];
        float v2 = row[lane + 128];
        float v3 = row[lane + 192];
        float m = fmaxf(fmaxf(v0, v1), fmaxf(v2, v3));
        #pragma unroll
        for (int off = 32; off; off >>= 1) m = fmaxf(m, __shfl_xor(m, off));
        const float cc = 1.4426950408889634f;
        float e0 = exp2f((v0 - m) * cc);
        float e1 = exp2f((v1 - m) * cc);
        float e2 = exp2f((v2 - m) * cc);
        float e3 = exp2f((v3 - m) * cc);
        float s = (e0 + e1) + (e2 + e3);
        #pragma unroll
        for (int off = 32; off; off >>= 1) s += __shfl_xor(s, off);
        const float r = 1.0f / s;
        row[lane]       = e0 * r;
        row[lane + 64]  = e1 * r;
        row[lane + 128] = e2 * r;
        row[lane + 192] = e3 * r;
    }
    __syncthreads();

    // ---- PV: thread = (d-quad dq = t&63 within half, j-group jh = t>>6) ----
    const int dq    = t & 63;
    const int jh    = t >> 6;              // == wave -> s_w reads wave-uniform
    const int dbase = dh * 256 + dq * 4;
    const float* __restrict__ vb = v + (size_t)b * N_ * D_ + dbase;

    float4 a0 = make_float4(0.f,0.f,0.f,0.f), a1 = a0, a2 = a0, a3 = a0;

#define PVROW(A, W)                                                            \
    A.x += (W).x * vv0.x + (W).y * vv1.x + (W).z * vv2.x + (W).w * vv3.x;      \
    A.y += (W).x * vv0.y + (W).y * vv1.y + (W).z * vv2.y + (W).w * vv3.y;      \
    A.z += (W).x * vv0.z + (W).y * vv1.z + (W).z * vv2.z + (W).w * vv3.z;      \
    A.w += (W).x * vv0.w + (W).y * vv1.w + (W).z * vv2.w + (W).w * vv3.w;

    #pragma unroll 2
    for (int jo = 0; jo < 64; jo += 4) {
        const int jj = jh * 64 + jo;
        const float4 vv0 = *(const float4*)(vb + (size_t)(jj + 0) * D_);
        const float4 vv1 = *(const float4*)(vb + (size_t)(jj + 1) * D_);
        const float4 vv2 = *(const float4*)(vb + (size_t)(jj + 2) * D_);
        const float4 vv3 = *(const float4*)(vb + (size_t)(jj + 3) * D_);
        const float4 w0 = *(const float4*)&s_w[0 * N_ + jj];
        const float4 w1 = *(const float4*)&s_w[1 * N_ + jj];
        const float4 w2 = *(const float4*)&s_w[2 * N_ + jj];
        const float4 w3 = *(const float4*)&s_w[3 * N_ + jj];
        PVROW(a0, w0) PVROW(a1, w1) PVROW(a2, w2) PVROW(a3, w3)
    }
#undef PVROW

    // ---- reduce 4 j-groups ----
    *(float4*)&s_part[jh * 1024 + 0 * 256 + dq * 4] = a0;
    *(float4*)&s_part[jh * 1024 + 1 * 256 + dq * 4] = a1;
    *(float4*)&s_part[jh * 1024 + 2 * 256 + dq * 4] = a2;
    *(float4*)&s_part[jh * 1024 + 3 * 256 + dq * 4] = a3;
    __syncthreads();

    {
        const int r  = t >> 6;             // row 0..3
        const int d4 = (t & 63) * 4;       // 0..252 within half
        const float4 p0 = *(const float4*)&s_part[0 * 1024 + r * 256 + d4];
        const float4 p1 = *(const float4*)&s_part[1 * 1024 + r * 256 + d4];
        const float4 p2 = *(const float4*)&s_part[2 * 1024 + r * 256 + d4];
        const float4 p3 = *(const float4*)&s_part[3 * 1024 + r * 256 + d4];
        float4 s;
        s.x = (p0.x + p1.x) + (p2.x + p3.x);
        s.y = (p0.y + p1.y) + (p2.y + p3.y);
        s.z = (p0.z + p1.z) + (p2.z + p3.z);
        s.w = (p0.w + p1.w) + (p2.w + p3.w);
        *(float4*)(out + ((size_t)(b * N_ + i0 + r)) * D_ + dh * 256 + d4) = s;
    }
}

// ---------- Fallback (round-1 kernel) if ws can't hold S (2 MB) ----------
__global__ __launch_bounds__(256, 2)
void manh_attn_legacy(const float* __restrict__ q,
                      const float* __restrict__ k,
                      const float* __restrict__ v,
                      float* __restrict__ out)
{
    __shared__ float s_mat[4][N_];
    const int t   = threadIdx.x;
    const int bid = blockIdx.x;
    const int b   = bid >> 6;
    const int i0  = (bid & 63) * 4;

    const float* __restrict__ krow  = k + ((size_t)(b * N_ + t)) * D_;
    const float* __restrict__ qbase = q + ((size_t)(b * N_ + i0)) * D_;

    float acc0 = 0.f, acc1 = 0.f, acc2 = 0.f, acc3 = 0.f;
    #pragma unroll 4
    for (int d = 0; d < D_; d += 4) {
        const float4 kv = *(const float4*)(krow + d);
        const float4 q0 = *(const float4*)(qbase + d);
        const float4 q1 = *(const float4*)(qbase + D_ + d);
        const float4 q2 = *(const float4*)(qbase + 2 * D_ + d);
        const float4 q3 = *(const float4*)(qbase + 3 * D_ + d);
        acc0 += (fabsf(q0.x - kv.x) + fabsf(q0.y - kv.y)) + (fabsf(q0.z - kv.z) + fabsf(q0.w - kv.w));
        acc1 += (fabsf(q1.x - kv.x) + fabsf(q1.y - kv.y)) + (fabsf(q1.z - kv.z) + fabsf(q1.w - kv.w));
        acc2 += (fabsf(q2.x - kv.x) + fabsf(q2.y - kv.y)) + (fabsf(q2.z - kv.z) + fabsf(q2.w - kv.w));
        acc3 += (fabsf(q3.x - kv.x) + fabsf(q3.y - kv.y)) + (fabsf(q3.z - kv.z) + fabsf(q3.w - kv.w));
    }
    s_mat[0][t] = -acc0; s_mat[1][t] = -acc1; s_mat[2][t] = -acc2; s_mat[3][t] = -acc3;
    __syncthreads();
    {
        const int w = t >> 6;
        const int l = t & 63;
        float v0 = s_mat[w][l], v1 = s_mat[w][l + 64], v2 = s_mat[w][l + 128], v3 = s_mat[w][l + 192];
        float m = fmaxf(fmaxf(v0, v1), fmaxf(v2, v3));
        #pragma unroll
        for (int off = 32; off; off >>= 1) m = fmaxf(m, __shfl_xor(m, off));
        const float c = 1.4426950408889634f;
        float e0 = exp2f((v0 - m) * c), e1 = exp2f((v1 - m) * c);
        float e2 = exp2f((v2 - m) * c), e3 = exp2f((v3 - m) * c);
        float s = (e0 + e1) + (e2 + e3);
        #pragma unroll
        for (int off = 32; off; off >>= 1) s += __shfl_xor(s, off);
        const float r = 1.0f / s;
        s_mat[w][l] = e0 * r; s_mat[w][l + 64] = e1 * r;
        s_mat[w][l + 128] = e2 * r; s_mat[w][l + 192] = e3 * r;
    }
    __syncthreads();
    const int ig = t >> 7;
    const int d0 = (t & 127) * 4;
    const float* __restrict__ vbase = v + ((size_t)b * N_) * D_ + d0;
    const float* __restrict__ wr0 = &s_mat[2 * ig][0];
    const float* __restrict__ wr1 = &s_mat[2 * ig + 1][0];
    float4 a0 = make_float4(0.f, 0.f, 0.f, 0.f);
    float4 a1 = make_float4(0.f, 0.f, 0.f, 0.f);
#define PV_STEP(W0, W1, VV)                                     \
    a0.x += (W0) * (VV).x; a0.y += (W0) * (VV).y;               \
    a0.z += (W0) * (VV).z; a0.w += (W0) * (VV).w;               \
    a1.x += (W1) * (VV).x; a1.y += (W1) * (VV).y;               \
    a1.z += (W1) * (VV).z; a1.w += (W1) * (VV).w;
    #pragma unroll 2
    for (int j = 0; j < N_; j += 4) {
        const float4 w0 = *(const float4*)(wr0 + j);
        const float4 w1 = *(const float4*)(wr1 + j);
        const float4 vv0 = *(const float4*)(vbase + (size_t)(j + 0) * D_);
        const float4 vv1 = *(const float4*)(vbase + (size_t)(j + 1) * D_);
        const float4 vv2 = *(const float4*)(vbase + (size_t)(j + 2) * D_);
        const float4 vv3 = *(const float4*)(vbase + (size_t)(j + 3) * D_);
        PV_STEP(w0.x, w1.x, vv0)
        PV_STEP(w0.y, w1.y, vv1)
        PV_STEP(w0.z, w1.z, vv2)
        PV_STEP(w0.w, w1.w, vv3)
    }
#undef PV_STEP
    float* op = out + ((size_t)(b * N_ + i0 + 2 * ig)) * D_ + d0;
    *(float4*)op        = a0;
    *(float4*)(op + D_) = a1;
}

extern "C" void kernel_launch(void* const* d_in, const int* in_sizes, int n_in,
                              void* d_out, int out_size, void* d_ws, size_t ws_size,
                              hipStream_t stream)
{
    const float* q = (const float*)d_in[0];
    const float* k = (const float*)d_in[1];
    const float* v = (const float*)d_in[2];
    float* out = (float*)d_out;

    const size_t S_bytes = (size_t)B_ * N_ * N_ * sizeof(float);
    if (ws_size >= S_bytes) {
        float* S = (float*)d_ws;
        manh_scores<<<dim3(1024), dim3(256), 0, stream>>>(q, k, S);
        manh_sm_pv <<<dim3(1024), dim3(256), 0, stream>>>(S, v, out);
    } else {
        manh_attn_legacy<<<dim3(B_ * 64), dim3(256), 0, stream>>>(q, k, v, out);
    }
}

// Round 13
// 36.677 us; speedup vs baseline: 1.6791x; 1.0404x over previous
//
#include <hip/hip_runtime.h>

#define B_ 8
#define N_ 256
#define D_ 512

// async 16B global -> LDS. FULL-WAVE ONLY (exec-masked LDS-DMA corrupts LDS).
__device__ __forceinline__ void load_lds_16B(const float* g, float* l)
{
    __builtin_amdgcn_global_load_lds(
        (const __attribute__((address_space(1))) void*)g,
        (__attribute__((address_space(3))) void*)l, 16, 0, 0);
}

// ================= Kernel A: scores S[b][i][j] = -sum_d |q-k| =============
// (verified R12) grid 1024: b=bid&7, itile=(bid>>3)&31 -> 8 rows, jq=bid>>8.
__global__ __launch_bounds__(256)
void manh_scores(const float* __restrict__ q,
                 const float* __restrict__ k,
                 float* __restrict__ S)
{
    __shared__ __align__(16) float s_k[2][4096];   // 32 KB: one 64-d chunk dbuf

    const int t     = threadIdx.x;
    const int b     = blockIdx.x & 7;          // batch -> XCD locality
    const int itile = (blockIdx.x >> 3) & 31;
    const int jq    = blockIdx.x >> 8;         // 0..3
    const int ibase = itile * 8;
    const int jbase = jq * 64;

    const float* __restrict__ kb = k + (size_t)b * N_ * D_;

    const int dg = (t & 3) ^ ((t >> 3) & 3);
    const float* ksrc = kb + (size_t)(jbase + (t >> 2)) * D_ + dg * 4;

#define STAGEA(cc, sb)                                              \
    {                                                               \
        load_lds_16B(ksrc + (cc) * 64,      &s_k[sb][4 * t]);       \
        load_lds_16B(ksrc + (cc) * 64 + 16, &s_k[sb][1024 + 4 * t]);\
        load_lds_16B(ksrc + (cc) * 64 + 32, &s_k[sb][2048 + 4 * t]);\
        load_lds_16B(ksrc + (cc) * 64 + 48, &s_k[sb][3072 + 4 * t]);\
    }

    STAGEA(0, 0)
    __syncthreads();

    const int w    = t >> 6;
    const int j    = t & 63;
    const int swz4 = ((j >> 1) & 3) << 2;
    const int row0 = __builtin_amdgcn_readfirstlane(ibase + 2 * w);
    const float* __restrict__ qrow = q + ((size_t)(b * N_ + row0)) * D_;

    float acc0 = 0.f, acc1 = 0.f;

    int buf = 0;
    for (int c = 0; c < 8; ++c) {
        if (c < 7) STAGEA(c + 1, buf ^ 1)

        const float* kcb = &s_k[buf][0];
        #pragma unroll
        for (int dgi = 0; dgi < 16; ++dgi) {
            const float4 k4 = *(const float4*)
                (kcb + (dgi >> 2) * 1024 + (j << 4) + (((dgi & 3) << 2) ^ swz4));
            const int doff = c * 64 + dgi * 4;
            const float4 q0 = *(const float4*)(qrow + doff);
            const float4 q1 = *(const float4*)(qrow + D_ + doff);
            acc0 += (fabsf(q0.x - k4.x) + fabsf(q0.y - k4.y)) +
                    (fabsf(q0.z - k4.z) + fabsf(q0.w - k4.w));
            acc1 += (fabsf(q1.x - k4.x) + fabsf(q1.y - k4.y)) +
                    (fabsf(q1.z - k4.z) + fabsf(q1.w - k4.w));
        }

        __syncthreads();
        buf ^= 1;
    }
#undef STAGEA

    float* Sp = S + (size_t)b * N_ * N_ + (size_t)(ibase + 2 * w) * N_ + jbase + j;
    Sp[0]  = -acc0;
    Sp[N_] = -acc1;
}

// ================= Kernel B: softmax(S) @ v, 8 rows/block ==================
// grid 512: b=bid&7, itile=(bid>>3)&31 -> 8 rows, dh=bid>>8 -> 256-d half.
// 512 thr (8 waves): softmax row w per wave; PV thread = (dq=t&63, jh=t>>6,
// 32 j each) x all 8 rows -> v half read exactly ONCE per block
// (16 MB/XCD vs 32 in R12). Reduce in 2 passes of 4 rows (32 KB scratch).
__global__ __launch_bounds__(512, 4)
void manh_sm_pv8(const float* __restrict__ S,
                 const float* __restrict__ v,
                 float* __restrict__ out)
{
    __shared__ __align__(16) float s_w[8 * N_];      // 8 KB
    __shared__ __align__(16) float s_part[8 * 1024]; // 32 KB: jh x 4rows x 256d

    const int t     = threadIdx.x;
    const int lane  = t & 63;
    const int w     = t >> 6;              // 0..7
    const int b     = blockIdx.x & 7;
    const int itile = (blockIdx.x >> 3) & 31;
    const int dh    = blockIdx.x >> 8;     // 0..1
    const int i0    = itile * 8;

    // ---- load scores: 8 rows x 256 j = 2048 floats, one float4/thread ----
    *(float4*)&s_w[4 * t] =
        *(const float4*)(S + (size_t)b * N_ * N_ + (size_t)i0 * N_ + 4 * t);
    __syncthreads();

    // ---- softmax: wave w handles row w ----
    {
        float* row = &s_w[w * N_];
        float v0 = row[lane];
        float v1 = row[lane + 64];
        float v2 = row[lane + 128];
        float v3 = row[lane + 192];
        float m = fmaxf(fmaxf(v0, v1), fmaxf(v2, v3));
        #pragma unroll
        for (int off = 32; off; off >>= 1) m = fmaxf(m, __shfl_xor(m, off));
        const float cc = 1.4426950408889634f;
        float e0 = exp2f((v0 - m) * cc);
        float e1 = exp2f((v1 - m) * cc);
        float e2 = exp2f((v2 - m) * cc);
        float e3 = exp2f((v3 - m) * cc);
        float s = (e0 + e1) + (e2 + e3);
        #pragma unroll
        for (int off = 32; off; off >>= 1) s += __shfl_xor(s, off);
        const float r = 1.0f / s;
        row[lane]       = e0 * r;
        row[lane + 64]  = e1 * r;
        row[lane + 128] = e2 * r;
        row[lane + 192] = e3 * r;
    }
    __syncthreads();

    // ---- PV: thread = (d-quad dq within half, j-group jh of 32 j) ----
    const int dq    = t & 63;
    const int jh    = t >> 6;              // == wave -> s_w reads wave-uniform
    const int dbase = dh * 256 + dq * 4;
    const float* __restrict__ vb = v + (size_t)b * N_ * D_ + dbase;

    float4 a0 = make_float4(0.f,0.f,0.f,0.f), a1 = a0, a2 = a0, a3 = a0;
    float4 a4 = a0, a5 = a0, a6 = a0, a7 = a0;

#define PVROW(A, W)                                                            \
    A.x += (W).x * vv0.x + (W).y * vv1.x + (W).z * vv2.x + (W).w * vv3.x;      \
    A.y += (W).x * vv0.y + (W).y * vv1.y + (W).z * vv2.y + (W).w * vv3.y;      \
    A.z += (W).x * vv0.z + (W).y * vv1.z + (W).z * vv2.z + (W).w * vv3.z;      \
    A.w += (W).x * vv0.w + (W).y * vv1.w + (W).z * vv2.w + (W).w * vv3.w;

    #pragma unroll 2
    for (int jo = 0; jo < 32; jo += 4) {
        const int jj = jh * 32 + jo;
        const float4 vv0 = *(const float4*)(vb + (size_t)(jj + 0) * D_);
        const float4 vv1 = *(const float4*)(vb + (size_t)(jj + 1) * D_);
        const float4 vv2 = *(const float4*)(vb + (size_t)(jj + 2) * D_);
        const float4 vv3 = *(const float4*)(vb + (size_t)(jj + 3) * D_);
        const float4 w0 = *(const float4*)&s_w[0 * N_ + jj];
        const float4 w1 = *(const float4*)&s_w[1 * N_ + jj];
        const float4 w2 = *(const float4*)&s_w[2 * N_ + jj];
        const float4 w3 = *(const float4*)&s_w[3 * N_ + jj];
        const float4 w4 = *(const float4*)&s_w[4 * N_ + jj];
        const float4 w5 = *(const float4*)&s_w[5 * N_ + jj];
        const float4 w6 = *(const float4*)&s_w[6 * N_ + jj];
        const float4 w7 = *(const float4*)&s_w[7 * N_ + jj];
        PVROW(a0, w0) PVROW(a1, w1) PVROW(a2, w2) PVROW(a3, w3)
        PVROW(a4, w4) PVROW(a5, w5) PVROW(a6, w6) PVROW(a7, w7)
    }
#undef PVROW

    // ---- reduce 8 j-groups, two 4-row passes ----
    // pass 0: rows 0..3
    *(float4*)&s_part[jh * 1024 + 0 * 256 + dq * 4] = a0;
    *(float4*)&s_part[jh * 1024 + 1 * 256 + dq * 4] = a1;
    *(float4*)&s_part[jh * 1024 + 2 * 256 + dq * 4] = a2;
    *(float4*)&s_part[jh * 1024 + 3 * 256 + dq * 4] = a3;
    __syncthreads();
    if (t < 256) {
        const int r  = t >> 6;             // 0..3
        const int d4 = (t & 63) * 4;
        float4 s = make_float4(0.f,0.f,0.f,0.f);
        #pragma unroll
        for (int g = 0; g < 8; ++g) {
            const float4 p = *(const float4*)&s_part[g * 1024 + r * 256 + d4];
            s.x += p.x; s.y += p.y; s.z += p.z; s.w += p.w;
        }
        *(float4*)(out + ((size_t)(b * N_ + i0 + r)) * D_ + dh * 256 + d4) = s;
    }
    __syncthreads();
    // pass 1: rows 4..7
    *(float4*)&s_part[jh * 1024 + 0 * 256 + dq * 4] = a4;
    *(float4*)&s_part[jh * 1024 + 1 * 256 + dq * 4] = a5;
    *(float4*)&s_part[jh * 1024 + 2 * 256 + dq * 4] = a6;
    *(float4*)&s_part[jh * 1024 + 3 * 256 + dq * 4] = a7;
    __syncthreads();
    if (t < 256) {
        const int r  = t >> 6;             // 0..3
        const int d4 = (t & 63) * 4;
        float4 s = make_float4(0.f,0.f,0.f,0.f);
        #pragma unroll
        for (int g = 0; g < 8; ++g) {
            const float4 p = *(const float4*)&s_part[g * 1024 + r * 256 + d4];
            s.x += p.x; s.y += p.y; s.z += p.z; s.w += p.w;
        }
        *(float4*)(out + ((size_t)(b * N_ + i0 + 4 + r)) * D_ + dh * 256 + d4) = s;
    }
}

// ---------- Fallback (round-1 kernel) if ws can't hold S (2 MB) ----------
__global__ __launch_bounds__(256, 2)
void manh_attn_legacy(const float* __restrict__ q,
                      const float* __restrict__ k,
                      const float* __restrict__ v,
                      float* __restrict__ out)
{
    __shared__ float s_mat[4][N_];
    const int t   = threadIdx.x;
    const int bid = blockIdx.x;
    const int b   = bid >> 6;
    const int i0  = (bid & 63) * 4;

    const float* __restrict__ krow  = k + ((size_t)(b * N_ + t)) * D_;
    const float* __restrict__ qbase = q + ((size_t)(b * N_ + i0)) * D_;

    float acc0 = 0.f, acc1 = 0.f, acc2 = 0.f, acc3 = 0.f;
    #pragma unroll 4
    for (int d = 0; d < D_; d += 4) {
        const float4 kv = *(const float4*)(krow + d);
        const float4 q0 = *(const float4*)(qbase + d);
        const float4 q1 = *(const float4*)(qbase + D_ + d);
        const float4 q2 = *(const float4*)(qbase + 2 * D_ + d);
        const float4 q3 = *(const float4*)(qbase + 3 * D_ + d);
        acc0 += (fabsf(q0.x - kv.x) + fabsf(q0.y - kv.y)) + (fabsf(q0.z - kv.z) + fabsf(q0.w - kv.w));
        acc1 += (fabsf(q1.x - kv.x) + fabsf(q1.y - kv.y)) + (fabsf(q1.z - kv.z) + fabsf(q1.w - kv.w));
        acc2 += (fabsf(q2.x - kv.x) + fabsf(q2.y - kv.y)) + (fabsf(q2.z - kv.z) + fabsf(q2.w - kv.w));
        acc3 += (fabsf(q3.x - kv.x) + fabsf(q3.y - kv.y)) + (fabsf(q3.z - kv.z) + fabsf(q3.w - kv.w));
    }
    s_mat[0][t] = -acc0; s_mat[1][t] = -acc1; s_mat[2][t] = -acc2; s_mat[3][t] = -acc3;
    __syncthreads();
    {
        const int w = t >> 6;
        const int l = t & 63;
        float v0 = s_mat[w][l], v1 = s_mat[w][l + 64], v2 = s_mat[w][l + 128], v3 = s_mat[w][l + 192];
        float m = fmaxf(fmaxf(v0, v1), fmaxf(v2, v3));
        #pragma unroll
        for (int off = 32; off; off >>= 1) m = fmaxf(m, __shfl_xor(m, off));
        const float c = 1.4426950408889634f;
        float e0 = exp2f((v0 - m) * c), e1 = exp2f((v1 - m) * c);
        float e2 = exp2f((v2 - m) * c), e3 = exp2f((v3 - m) * c);
        float s = (e0 + e1) + (e2 + e3);
        #pragma unroll
        for (int off = 32; off; off >>= 1) s += __shfl_xor(s, off);
        const float r = 1.0f / s;
        s_mat[w][l] = e0 * r; s_mat[w][l + 64] = e1 * r;
        s_mat[w][l + 128] = e2 * r; s_mat[w][l + 192] = e3 * r;
    }
    __syncthreads();
    const int ig = t >> 7;
    const int d0 = (t & 127) * 4;
    const float* __restrict__ vbase = v + ((size_t)b * N_) * D_ + d0;
    const float* __restrict__ wr0 = &s_mat[2 * ig][0];
    const float* __restrict__ wr1 = &s_mat[2 * ig + 1][0];
    float4 a0 = make_float4(0.f, 0.f, 0.f, 0.f);
    float4 a1 = make_float4(0.f, 0.f, 0.f, 0.f);
#define PV_STEP(W0, W1, VV)                                     \
    a0.x += (W0) * (VV).x; a0.y += (W0) * (VV).y;               \
    a0.z += (W0) * (VV).z; a0.w += (W0) * (VV).w;               \
    a1.x += (W1) * (VV).x; a1.y += (W1) * (VV).y;               \
    a1.z += (W1) * (VV).z; a1.w += (W1) * (VV).w;
    #pragma unroll 2
    for (int j = 0; j < N_; j += 4) {
        const float4 w0 = *(const float4*)(wr0 + j);
        const float4 w1 = *(const float4*)(wr1 + j);
        const float4 vv0 = *(const float4*)(vbase + (size_t)(j + 0) * D_);
        const float4 vv1 = *(const float4*)(vbase + (size_t)(j + 1) * D_);
        const float4 vv2 = *(const float4*)(vbase + (size_t)(j + 2) * D_);
        const float4 vv3 = *(const float4*)(vbase + (size_t)(j + 3) * D_);
        PV_STEP(w0.x, w1.x, vv0)
        PV_STEP(w0.y, w1.y, vv1)
        PV_STEP(w0.z, w1.z, vv2)
        PV_STEP(w0.w, w1.w, vv3)
    }
#undef PV_STEP
    float* op = out + ((size_t)(b * N_ + i0 + 2 * ig)) * D_ + d0;
    *(float4*)op        = a0;
    *(float4*)(op + D_) = a1;
}

extern "C" void kernel_launch(void* const* d_in, const int* in_sizes, int n_in,
                              void* d_out, int out_size, void* d_ws, size_t ws_size,
                              hipStream_t stream)
{
    const float* q = (const float*)d_in[0];
    const float* k = (const float*)d_in[1];
    const float* v = (const float*)d_in[2];
    float* out = (float*)d_out;

    const size_t S_bytes = (size_t)B_ * N_ * N_ * sizeof(float);
    if (ws_size >= S_bytes) {
        float* S = (float*)d_ws;
        manh_scores<<<dim3(1024), dim3(256), 0, stream>>>(q, k, S);
        manh_sm_pv8<<<dim3(512), dim3(512), 0, stream>>>(S, v, out);
    } else {
        manh_attn_legacy<<<dim3(B_ * 64), dim3(256), 0, stream>>>(q, k, v, out);
    }
}